// Round 1
// 180.585 us; speedup vs baseline: 1.0264x; 1.0264x over previous
//
#include <hip/hip_runtime.h>

#define B_ 8
#define N_ 8192
#define S_ 2048
#define D_ 256
#define EPS_ 1e-8f
#define TILE_Q 64
#define NTHR 512
#define NCH 8
#define CHUNK (S_ / NCH)   /* 256 candidates per wave */
#define HALF (CHUNK / 2)   /* 128: two independent insert chains */

// Branchless stable top-3 insert, med3 network. Sorted invariant d0<=d1<=d2.
// Strict '<' => incumbent (earlier index) wins ties, matching jax.lax.top_k.
__device__ __forceinline__ void insert3(float dd, int s,
                                        float& d0, float& d1, float& d2,
                                        int& i0, int& i1, int& i2) {
    bool ca = dd < d0;
    bool cb = dd < d1;
    bool cc = dd < d2;
    int i2n = cb ? i1 : (cc ? s : i2);
    int i1n = ca ? i0 : (cb ? s : i1);
    int i0n = ca ? s : i0;
    d2 = fminf(d2, fmaxf(d1, dd));
    d1 = __builtin_amdgcn_fmed3f(d0, d1, dd);
    d0 = fminf(d0, dd);
    i0 = i0n; i1 = i1n; i2 = i2n;
}

__global__ __launch_bounds__(NTHR, 8) void fp_interp_kernel(
    const float* __restrict__ xyz1,     // [B,3,N]
    const float* __restrict__ xyz2,     // [B,3,S]
    const float* __restrict__ points2,  // [B,S,D]
    float* __restrict__ out)            // [B,N,D]
{
    // R2 restructure: candidate xyz is wave-uniform -> deliver via the SCALAR
    // pipe (s_load, scalar cache) instead of 16B/lane LDS broadcast. Only
    // |b|^2 stays in LDS, read as one ds_read_b128 per FOUR candidates.
    // LDS->VGPR broadcast traffic drops 16B -> 4B per wave-candidate (4x);
    // the ds_read->fma lgkmcnt chain that throttled the old loop is gone.
    // rank key = |b|^2 - 2*a.b (per-query |a|^2 re-added in phase B).
    // key = fmaf(-2ax, bx, fmaf(-2ay, by, fmaf(-2az, bz, nn))) is bitwise
    // identical to the proven tile form (scaling by exact -2 commutes through
    // fma rounding), so neighbor selection reproduces exactly.
    __shared__ float s_nn[S_] __attribute__((aligned(16)));   // 8 KB
    __shared__ float s_pd[NCH][3][TILE_Q];                    // partial dists
    __shared__ int   s_pi[NCH][3][TILE_Q];                    // partial idx
    __shared__ float s_w[3][TILE_Q];
    __shared__ int   s_idx[3][TILE_Q];

    // batch-per-XCD swizzle: each XCD's points2 gather set is one 2 MB slice.
    // Same-CU blocks (stride-8 blockIdx) share one batch -> xyz2 scalar-cache
    // and L2 locality for the s_loads comes free.
    const int b  = blockIdx.x & 7;
    const int n0 = (blockIdx.x >> 3) * TILE_Q;
    const int t = threadIdx.x;
    const int wave = t >> 6, lane = t & 63;

    // Stage |b|^2 only (coalesced reads; same fma order as before).
    const float* x2 = xyz2 + (size_t)b * 3 * S_;
    for (int s = t; s < S_; s += NTHR) {
        float bx = x2[s], by = x2[S_ + s], bz = x2[2 * S_ + s];
        s_nn[s] = fmaf(bz, bz, fmaf(by, by, bx * bx));
    }
    __syncthreads();

    // Phase A: wave w scans its 256-candidate chunk for 64 queries
    // (lane<->query). Candidate coords come from SGPRs (1 sgpr operand per
    // v_fma is legal); nn comes from LDS as float4 per 4 candidates.
    const int n = n0 + lane;
    const float* x1 = xyz1 + (size_t)b * 3 * N_;
    const float ax = x1[n], ay = x1[N_ + n], az = x1[2 * N_ + n];
    const float ax2 = -2.0f * ax, ay2 = -2.0f * ay, az2 = -2.0f * az;

    float a0 = __builtin_inff(), a1 = __builtin_inff(), a2 = __builtin_inff();
    int ja0 = 0, ja1 = 0, ja2 = 0;
    float c0 = __builtin_inff(), c1 = __builtin_inff(), c2 = __builtin_inff();
    int jc0 = 0, jc1 = 0, jc2 = 0;

    // readfirstlane forces the chunk base into an SGPR so the candidate
    // loads below are provably uniform -> s_load (scalar cache), not VMEM.
    const int wu   = __builtin_amdgcn_readfirstlane(wave);
    const int sbeg = wu * CHUNK;
    const float* bxp = x2;
    const float* byp = x2 + S_;
    const float* bzp = x2 + 2 * S_;
    const float4* nn4 = (const float4*)s_nn;
    const int g0 = sbeg >> 2;

    #pragma unroll 2
    for (int g = 0; g < HALF / 4; ++g) {
        float4 nl = nn4[g0 + g];
        float4 nh = nn4[g0 + (HALF >> 2) + g];
        #pragma unroll
        for (int u = 0; u < 4; ++u) {
            const int sl = sbeg + 4 * g + u;
            const int sh = sl + HALF;
            const float nlu = (&nl.x)[u];
            const float nhu = (&nh.x)[u];
            float kl = fmaf(ax2, bxp[sl],
                       fmaf(ay2, byp[sl], fmaf(az2, bzp[sl], nlu)));
            float kh = fmaf(ax2, bxp[sh],
                       fmaf(ay2, byp[sh], fmaf(az2, bzp[sh], nhu)));
            insert3(kl, sl, a0, a1, a2, ja0, ja1, ja2);
            insert3(kh, sh, c0, c1, c2, jc0, jc1, jc2);
        }
    }
    // merge hi chain into lo (index-stable: all hi indices larger)
    insert3(c0, jc0, a0, a1, a2, ja0, ja1, ja2);
    insert3(c1, jc1, a0, a1, a2, ja0, ja1, ja2);
    insert3(c2, jc2, a0, a1, a2, ja0, ja1, ja2);

    s_pd[wave][0][lane] = a0;
    s_pd[wave][1][lane] = a1;
    s_pd[wave][2][lane] = a2;
    s_pi[wave][0][lane] = ja0;
    s_pi[wave][1][lane] = ja1;
    s_pi[wave][2][lane] = ja2;
    __syncthreads();

    // Phase B: merge 8 chunk-triples per query (ascending chunk order =>
    // ascending index blocks => stable). Recover true distance = key + |a|^2.
    if (t < TILE_Q) {
        float e0 = __builtin_inff(), e1 = __builtin_inff(), e2 = __builtin_inff();
        int j0 = 0, j1 = 0, j2 = 0;
        #pragma unroll
        for (int c = 0; c < NCH; ++c) {
            #pragma unroll
            for (int k = 0; k < 3; ++k)
                insert3(s_pd[c][k][t], s_pi[c][k][t],
                        e0, e1, e2, j0, j1, j2);
        }
        const int nq = n0 + t;
        float qx = x1[nq], qy = x1[N_ + nq], qz = x1[2 * N_ + nq];
        float n1 = fmaf(qz, qz, fmaf(qy, qy, qx * qx));
        float r0 = __fdiv_rn(1.0f, __fadd_rn(__fadd_rn(e0, n1), EPS_));
        float r1 = __fdiv_rn(1.0f, __fadd_rn(__fadd_rn(e1, n1), EPS_));
        float r2 = __fdiv_rn(1.0f, __fadd_rn(__fadd_rn(e2, n1), EPS_));
        float rs = __fadd_rn(__fadd_rn(r0, r1), r2);
        s_w[0][t] = __fdiv_rn(r0, rs);
        s_w[1][t] = __fdiv_rn(r1, rs);
        s_w[2][t] = __fdiv_rn(r2, rs);
        s_idx[0][t] = j0; s_idx[1][t] = j1; s_idx[2][t] = j2;
    }
    __syncthreads();

    // Phase C: gather + weighted sum. One wave per query row; 64 lanes x
    // float4 covers D=256. Gather set is L2-resident per XCD.
    const float* p2 = points2 + (size_t)b * S_ * D_;
    float* op = out + ((size_t)b * N_ + n0) * D_;
    for (int q = wave; q < TILE_Q; q += NCH) {
        float w0 = s_w[0][q], w1 = s_w[1][q], w2 = s_w[2][q];
        const float4* f0 = (const float4*)(p2 + (size_t)s_idx[0][q] * D_) + lane;
        const float4* f1 = (const float4*)(p2 + (size_t)s_idx[1][q] * D_) + lane;
        const float4* f2 = (const float4*)(p2 + (size_t)s_idx[2][q] * D_) + lane;
        float4 v0 = *f0, v1 = *f1, v2 = *f2;
        float4 r;
        r.x = w0 * v0.x + w1 * v1.x + w2 * v2.x;
        r.y = w0 * v0.y + w1 * v1.y + w2 * v2.y;
        r.z = w0 * v0.z + w1 * v1.z + w2 * v2.z;
        r.w = w0 * v0.w + w1 * v1.w + w2 * v2.w;
        *((float4*)(op + (size_t)q * D_) + lane) = r;
    }
}

extern "C" void kernel_launch(void* const* d_in, const int* in_sizes, int n_in,
                              void* d_out, int out_size, void* d_ws, size_t ws_size,
                              hipStream_t stream) {
    const float* xyz1    = (const float*)d_in[0];
    const float* xyz2    = (const float*)d_in[1];
    // d_in[2] = points1 is unused by the reference output.
    const float* points2 = (const float*)d_in[3];
    float* out = (float*)d_out;

    dim3 grid(B_ * (N_ / TILE_Q));  // 1024 blocks, 4 per CU at 512 thr
    dim3 block(NTHR);
    fp_interp_kernel<<<grid, block, 0, stream>>>(xyz1, xyz2, points2, out);
}

// Round 2
// 179.189 us; speedup vs baseline: 1.0344x; 1.0078x over previous
//
#include <hip/hip_runtime.h>

#define B_ 8
#define N_ 8192
#define S_ 2048
#define D_ 256
#define EPS_ 1e-8f
#define TILE_Q 64
#define NTHR 512
#define NCH 8
#define CHUNK (S_ / NCH)   /* 256 candidates per wave */
#define HALF (CHUNK / 2)   /* 128: two independent insert chains */

// Branchless stable top-3 insert, med3 network. Sorted invariant d0<=d1<=d2.
// Strict '<' => incumbent (earlier index) wins ties, matching jax.lax.top_k.
__device__ __forceinline__ void insert3(float dd, int s,
                                        float& d0, float& d1, float& d2,
                                        int& i0, int& i1, int& i2) {
    bool ca = dd < d0;
    bool cb = dd < d1;
    bool cc = dd < d2;
    int i2n = cb ? i1 : (cc ? s : i2);
    int i1n = ca ? i0 : (cb ? s : i1);
    int i0n = ca ? s : i0;
    d2 = fminf(d2, fmaxf(d1, dd));
    d1 = __builtin_amdgcn_fmed3f(d0, d1, dd);
    d0 = fminf(d0, dd);
    i0 = i0n; i1 = i1n; i2 = i2n;
}

// Prep: cand[b][s] = (-2bx, -2by, -2bz, |b|^2), one contiguous float4 stream.
// 256 KB total -> L2-resident per XCD slice; removes ALL per-candidate
// address math and DS traffic from the main kernel's hot loop.
__global__ __launch_bounds__(256) void prep_kernel(
    const float* __restrict__ xyz2, float4* __restrict__ cand) {
    const int i = blockIdx.x * 256 + threadIdx.x;   // 0 .. B_*S_-1
    const int b = i >> 11, s = i & (S_ - 1);
    const float* x2 = xyz2 + (size_t)b * 3 * S_;
    float bx = x2[s], by = x2[S_ + s], bz = x2[2 * S_ + s];
    float nn = fmaf(bz, bz, fmaf(by, by, bx * bx));
    cand[i] = make_float4(-2.0f * bx, -2.0f * by, -2.0f * bz, nn);
}

template <bool WS>
__global__ __launch_bounds__(NTHR, 8) void fp_interp_kernel(
    const float* __restrict__ xyz1,     // [B,3,N]
    const float* __restrict__ xyz2,     // [B,3,S]
    const float* __restrict__ points2,  // [B,S,D]
    const float4* __restrict__ cand,    // [B,S] prepped stream (WS path)
    float* __restrict__ out)            // [B,N,D]
{
    // R3: phase A is a pure linear SMEM stream. Candidate float4s are
    // wave-uniform -> s_load_dwordx4 (merged to x8/x16 across the unroll),
    // batched waits, zero DS ops, zero per-candidate address math.
    // key = fmaf(ax,-2bx, fmaf(ay,-2by, fmaf(az,-2bz, nn))): exact products
    // => bitwise-identical selection to the proven R1 expansion form.
    __shared__ float s_nn[S_] __attribute__((aligned(16)));   // WS=false only
    __shared__ float s_pd[NCH][3][TILE_Q];                    // partial dists
    __shared__ int   s_pi[NCH][3][TILE_Q];                    // partial idx
    __shared__ float s_w[3][TILE_Q];
    __shared__ int   s_idx[3][TILE_Q];

    // batch-per-XCD swizzle: each XCD's points2 gather set is one 2 MB slice.
    const int b  = blockIdx.x & 7;
    const int n0 = (blockIdx.x >> 3) * TILE_Q;
    const int t = threadIdx.x;
    const int wave = t >> 6, lane = t & 63;

    const float* x2 = xyz2 + (size_t)b * 3 * S_;
    if constexpr (!WS) {
        // Fallback staging (proven R1 path): |b|^2 tile in LDS.
        for (int s = t; s < S_; s += NTHR) {
            float bx = x2[s], by = x2[S_ + s], bz = x2[2 * S_ + s];
            s_nn[s] = fmaf(bz, bz, fmaf(by, by, bx * bx));
        }
        __syncthreads();
    }

    // Phase A: wave w scans its 256-candidate chunk for 64 queries
    // (lane<->query), two independent insert chains for ILP.
    const int n = n0 + lane;
    const float* x1 = xyz1 + (size_t)b * 3 * N_;
    const float ax = x1[n], ay = x1[N_ + n], az = x1[2 * N_ + n];

    float a0 = __builtin_inff(), a1 = __builtin_inff(), a2 = __builtin_inff();
    int ja0 = 0, ja1 = 0, ja2 = 0;
    float c0 = __builtin_inff(), c1 = __builtin_inff(), c2 = __builtin_inff();
    int jc0 = 0, jc1 = 0, jc2 = 0;

    // readfirstlane: provably wave-uniform chunk base -> scalar loads.
    const int wu   = __builtin_amdgcn_readfirstlane(wave);
    const int sbeg = wu * CHUNK;

    if constexpr (WS) {
        const float4* cw = cand + (size_t)b * S_;
        #pragma unroll 4
        for (int j = 0; j < HALF; ++j) {
            float4 cl = cw[sbeg + j];          // uniform -> s_load (64B/4 cand)
            float4 ch = cw[sbeg + HALF + j];
            float kl = fmaf(ax, cl.x, fmaf(ay, cl.y, fmaf(az, cl.z, cl.w)));
            float kh = fmaf(ax, ch.x, fmaf(ay, ch.y, fmaf(az, ch.z, ch.w)));
            insert3(kl, sbeg + j,        a0, a1, a2, ja0, ja1, ja2);
            insert3(kh, sbeg + HALF + j, c0, c1, c2, jc0, jc1, jc2);
        }
    } else {
        const float ax2 = -2.0f * ax, ay2 = -2.0f * ay, az2 = -2.0f * az;
        const float* bxp = x2;
        const float* byp = x2 + S_;
        const float* bzp = x2 + 2 * S_;
        const float4* nn4 = (const float4*)s_nn;
        const int g0 = sbeg >> 2;
        #pragma unroll 2
        for (int g = 0; g < HALF / 4; ++g) {
            float4 nl = nn4[g0 + g];
            float4 nh = nn4[g0 + (HALF >> 2) + g];
            #pragma unroll
            for (int u = 0; u < 4; ++u) {
                const int sl = sbeg + 4 * g + u;
                const int sh = sl + HALF;
                const float nlu = (&nl.x)[u];
                const float nhu = (&nh.x)[u];
                float kl = fmaf(ax2, bxp[sl],
                           fmaf(ay2, byp[sl], fmaf(az2, bzp[sl], nlu)));
                float kh = fmaf(ax2, bxp[sh],
                           fmaf(ay2, byp[sh], fmaf(az2, bzp[sh], nhu)));
                insert3(kl, sl, a0, a1, a2, ja0, ja1, ja2);
                insert3(kh, sh, c0, c1, c2, jc0, jc1, jc2);
            }
        }
    }
    // merge hi chain into lo (index-stable: all hi indices larger)
    insert3(c0, jc0, a0, a1, a2, ja0, ja1, ja2);
    insert3(c1, jc1, a0, a1, a2, ja0, ja1, ja2);
    insert3(c2, jc2, a0, a1, a2, ja0, ja1, ja2);

    s_pd[wave][0][lane] = a0;
    s_pd[wave][1][lane] = a1;
    s_pd[wave][2][lane] = a2;
    s_pi[wave][0][lane] = ja0;
    s_pi[wave][1][lane] = ja1;
    s_pi[wave][2][lane] = ja2;
    __syncthreads();

    // Phase B: merge 8 chunk-triples per query (ascending chunk order =>
    // ascending index blocks => stable). Recover true distance = key + |a|^2.
    if (t < TILE_Q) {
        float e0 = __builtin_inff(), e1 = __builtin_inff(), e2 = __builtin_inff();
        int j0 = 0, j1 = 0, j2 = 0;
        #pragma unroll
        for (int c = 0; c < NCH; ++c) {
            #pragma unroll
            for (int k = 0; k < 3; ++k)
                insert3(s_pd[c][k][t], s_pi[c][k][t],
                        e0, e1, e2, j0, j1, j2);
        }
        const int nq = n0 + t;
        float qx = x1[nq], qy = x1[N_ + nq], qz = x1[2 * N_ + nq];
        float n1 = fmaf(qz, qz, fmaf(qy, qy, qx * qx));
        float r0 = __fdiv_rn(1.0f, __fadd_rn(__fadd_rn(e0, n1), EPS_));
        float r1 = __fdiv_rn(1.0f, __fadd_rn(__fadd_rn(e1, n1), EPS_));
        float r2 = __fdiv_rn(1.0f, __fadd_rn(__fadd_rn(e2, n1), EPS_));
        float rs = __fadd_rn(__fadd_rn(r0, r1), r2);
        s_w[0][t] = __fdiv_rn(r0, rs);
        s_w[1][t] = __fdiv_rn(r1, rs);
        s_w[2][t] = __fdiv_rn(r2, rs);
        s_idx[0][t] = j0; s_idx[1][t] = j1; s_idx[2][t] = j2;
    }
    __syncthreads();

    // Phase C: gather + weighted sum. One wave per query row; 64 lanes x
    // float4 covers D=256. Gather set is L2-resident per XCD.
    const float* p2 = points2 + (size_t)b * S_ * D_;
    float* op = out + ((size_t)b * N_ + n0) * D_;
    for (int q = wave; q < TILE_Q; q += NCH) {
        float w0 = s_w[0][q], w1 = s_w[1][q], w2 = s_w[2][q];
        const float4* f0 = (const float4*)(p2 + (size_t)s_idx[0][q] * D_) + lane;
        const float4* f1 = (const float4*)(p2 + (size_t)s_idx[1][q] * D_) + lane;
        const float4* f2 = (const float4*)(p2 + (size_t)s_idx[2][q] * D_) + lane;
        float4 v0 = *f0, v1 = *f1, v2 = *f2;
        float4 r;
        r.x = w0 * v0.x + w1 * v1.x + w2 * v2.x;
        r.y = w0 * v0.y + w1 * v1.y + w2 * v2.y;
        r.z = w0 * v0.z + w1 * v1.z + w2 * v2.z;
        r.w = w0 * v0.w + w1 * v1.w + w2 * v2.w;
        *((float4*)(op + (size_t)q * D_) + lane) = r;
    }
}

extern "C" void kernel_launch(void* const* d_in, const int* in_sizes, int n_in,
                              void* d_out, int out_size, void* d_ws, size_t ws_size,
                              hipStream_t stream) {
    const float* xyz1    = (const float*)d_in[0];
    const float* xyz2    = (const float*)d_in[1];
    // d_in[2] = points1 is unused by the reference output.
    const float* points2 = (const float*)d_in[3];
    float* out = (float*)d_out;

    dim3 grid(B_ * (N_ / TILE_Q));  // 1024 blocks, 4 per CU at 512 thr
    dim3 block(NTHR);

    const size_t need = (size_t)B_ * S_ * sizeof(float4);   // 256 KB
    if (d_ws && ws_size >= need) {
        float4* cand = (float4*)d_ws;
        prep_kernel<<<dim3(B_ * S_ / 256), dim3(256), 0, stream>>>(xyz2, cand);
        fp_interp_kernel<true><<<grid, block, 0, stream>>>(
            xyz1, xyz2, points2, cand, out);
    } else {
        fp_interp_kernel<false><<<grid, block, 0, stream>>>(
            xyz1, xyz2, points2, nullptr, out);
    }
}